// Round 1
// baseline (380.980 us; speedup 1.0000x reference)
//
#include <hip/hip_runtime.h>
#include <cstdint>
#include <cstddef>

#define T_TOK 2048
#define DMODEL 1024
#define NEXP 8
#define HID 2048
#define DUMP_ID 4096   // assignment-id for padding rows (token row 2048 = zeros)

typedef __bf16 bf16x8 __attribute__((ext_vector_type(8)));
typedef float f32x4 __attribute__((ext_vector_type(4)));

__device__ __forceinline__ unsigned short f2bf(float f) {
    union { float f; unsigned int u; } v; v.f = f;
    unsigned int u = v.u;
    unsigned int r = (u + 0x7FFFu + ((u >> 16) & 1u)) >> 16;  // RNE
    return (unsigned short)r;
}

__device__ __forceinline__ void gl2lds16(const void* g, void* l) {
    __builtin_amdgcn_global_load_lds(
        (const __attribute__((address_space(1))) void*)g,
        (__attribute__((address_space(3))) void*)l,
        16, 0, 0);
}

// ---------------------------------------------------------------- init ------
__global__ void init_k(int* __restrict__ counts, int* __restrict__ list,
                       unsigned short* __restrict__ xb_dump_row) {
    int i = blockIdx.x * blockDim.x + threadIdx.x;
    if (i < NEXP) counts[i] = 0;
    if (i < NEXP * T_TOK) list[i] = DUMP_ID;
    if (i < DMODEL) xb_dump_row[i] = 0;  // zero token row used by padded slots
}

// -------------------------------------------------------------- router ------
// one wave (64 threads) per token: fp32 GEMV vs gate_w, sigmoid, top-2,
// atomic slot assignment into per-expert lists; also converts x row to bf16.
__global__ __launch_bounds__(64) void router_k(
    const float* __restrict__ x, const float* __restrict__ gw,
    const float* __restrict__ bias, unsigned short* __restrict__ xb,
    int* __restrict__ counts, int* __restrict__ list, float* __restrict__ w2) {
    const int t = blockIdx.x;
    const int lane = threadIdx.x;
    const float* xr = x + (size_t)t * DMODEL;
    float acc[NEXP];
#pragma unroll
    for (int e = 0; e < NEXP; ++e) acc[e] = 0.f;
#pragma unroll
    for (int j = 0; j < DMODEL / 64; ++j) {
        int i = lane + j * 64;
        float xv = xr[i];
        xb[(size_t)t * DMODEL + i] = f2bf(xv);
#pragma unroll
        for (int e = 0; e < NEXP; ++e) acc[e] += xv * gw[e * DMODEL + i];
    }
#pragma unroll
    for (int e = 0; e < NEXP; ++e)
        for (int off = 32; off > 0; off >>= 1) acc[e] += __shfl_xor(acc[e], off, 64);
    if (lane == 0) {
        float sc[NEXP], bi[NEXP];
#pragma unroll
        for (int e = 0; e < NEXP; ++e) {
            sc[e] = 1.f / (1.f + expf(-acc[e]));
            bi[e] = sc[e] + bias[e];
        }
        int e0 = 0;
        for (int e = 1; e < NEXP; ++e) if (bi[e] > bi[e0]) e0 = e;  // ties -> lowest idx
        int e1 = -1;
        for (int e = 0; e < NEXP; ++e) {
            if (e == e0) continue;
            if (e1 < 0 || bi[e] > bi[e1]) e1 = e;
        }
        int s0 = atomicAdd(&counts[e0], 1);
        list[e0 * T_TOK + s0] = 2 * t;
        int s1 = atomicAdd(&counts[e1], 1);
        list[e1 * T_TOK + s1] = 2 * t + 1;
        w2[2 * t]     = sc[e0] * sc[e0];
        w2[2 * t + 1] = sc[e1] * sc[e1];
    }
}

// ------------------------------------------------- weight fp32 -> bf16 ------
__global__ void convert_w(const float4* __restrict__ wu, const float4* __restrict__ wd,
                          ushort4* __restrict__ wub, ushort4* __restrict__ wdb, int n4) {
    int i = blockIdx.x * blockDim.x + threadIdx.x;
    int stride = gridDim.x * blockDim.x;
    for (; i < 2 * n4; i += stride) {
        bool second = (i >= n4);
        int idx = second ? i - n4 : i;
        float4 f = second ? wd[idx] : wu[idx];
        ushort4 o;
        o.x = f2bf(f.x); o.y = f2bf(f.y); o.z = f2bf(f.z); o.w = f2bf(f.w);
        if (second) wdb[idx] = o; else wub[idx] = o;
    }
}

// ---------------------------------------------------- grouped GEMM ----------
// MODE 0 (up):   A = xb gathered (row = id>>1, K=1024), B = wu_bf16[e] (N=2048 x K)
//                epilogue: h[id][n] = bf16( w2[id] * relu(v)^2 )
// MODE 1 (down): A = h gathered (row = id, K=2048),    B = wd_bf16[e] (N=1024 x K)
//                epilogue: c[id][n] = v (fp32)
// 128x128 tile, BK=32, 4 waves each 64x64 (4x4 of 16x16x32 MFMA).
template <int MODE>
__global__ __launch_bounds__(256, 2) void moe_gemm(
    const unsigned short* __restrict__ Asrc, const int* __restrict__ list,
    const int* __restrict__ counts, const unsigned short* __restrict__ Ball,
    const float* __restrict__ w2, unsigned short* __restrict__ Hout,
    float* __restrict__ Cout) {
    constexpr int K = (MODE == 0) ? DMODEL : HID;
    const int e = blockIdx.z;
    const int m0 = blockIdx.y * 128;
    if (m0 >= counts[e]) return;
    const int n0 = blockIdx.x * 128;
    const int tid = threadIdx.x;
    const int lane = tid & 63;
    const int w = tid >> 6;

    __shared__ unsigned short As[128 * 32];
    __shared__ unsigned short Bs[128 * 32];

    const int* mylist = list + e * T_TOK + m0;
    const unsigned short* B = Ball + (size_t)e * HID * DMODEL;

    // staging source pointers: seg = it*256 + tid; row = seg>>2; kseg = seg&3
    const unsigned short* ap[2];
    const unsigned short* bp[2];
#pragma unroll
    for (int it = 0; it < 2; ++it) {
        int seg = it * 256 + tid;
        int row = seg >> 2;
        int ks = (seg & 3) * 8;
        int id = mylist[row];
        int arow = (MODE == 0) ? (id >> 1) : id;
        ap[it] = Asrc + (size_t)arow * K + ks;
        bp[it] = B + (size_t)(n0 + row) * K + ks;
    }
    // wave-uniform LDS bases (lane*16B appended by HW)
    unsigned short* ldsA[2] = { As + (w * 64) * 8, As + (256 + w * 64) * 8 };
    unsigned short* ldsB[2] = { Bs + (w * 64) * 8, Bs + (256 + w * 64) * 8 };

    f32x4 acc[4][4];
#pragma unroll
    for (int i = 0; i < 4; ++i)
#pragma unroll
        for (int j = 0; j < 4; ++j) acc[i][j] = f32x4{0.f, 0.f, 0.f, 0.f};

    const int wm = (w >> 1) * 64;
    const int wn = (w & 1) * 64;
    const int quad = lane >> 4;
    const int lrow = lane & 15;

    for (int kt = 0; kt < K / 32; ++kt) {
        gl2lds16(ap[0], ldsA[0]);
        gl2lds16(ap[1], ldsA[1]);
        gl2lds16(bp[0], ldsB[0]);
        gl2lds16(bp[1], ldsB[1]);
        ap[0] += 32; ap[1] += 32; bp[0] += 32; bp[1] += 32;
        __syncthreads();  // drains vmcnt -> staged data visible
        bf16x8 af[4], bf[4];
#pragma unroll
        for (int i = 0; i < 4; ++i) {
            af[i] = *(const bf16x8*)(As + (wm + i * 16 + lrow) * 32 + quad * 8);
            bf[i] = *(const bf16x8*)(Bs + (wn + i * 16 + lrow) * 32 + quad * 8);
        }
#pragma unroll
        for (int i = 0; i < 4; ++i)
#pragma unroll
            for (int j = 0; j < 4; ++j)
                acc[i][j] = __builtin_amdgcn_mfma_f32_16x16x32_bf16(af[i], bf[j],
                                                                    acc[i][j], 0, 0, 0);
        __syncthreads();  // protect LDS before next stage overwrites
    }

    // epilogue: C/D mapping col = lane&15, row = (lane>>4)*4 + reg
#pragma unroll
    for (int i = 0; i < 4; ++i) {
        int mbase = wm + i * 16 + (lane >> 4) * 4;
        int ids[4];
        float ww[4];
#pragma unroll
        for (int r = 0; r < 4; ++r) {
            ids[r] = mylist[mbase + r];
            if (MODE == 0) ww[r] = w2[ids[r]];
        }
#pragma unroll
        for (int j = 0; j < 4; ++j) {
            int n = n0 + wn + j * 16 + (lane & 15);
#pragma unroll
            for (int r = 0; r < 4; ++r) {
                float v = acc[i][j][r];
                if (MODE == 0) {
                    v = (v > 0.f) ? v * v * ww[r] : 0.f;
                    Hout[(size_t)ids[r] * HID + n] = f2bf(v);
                } else {
                    Cout[(size_t)ids[r] * DMODEL + n] = v;
                }
            }
        }
    }
}

// -------------------------------------------------------------- combine -----
__global__ void combine_k(const float4* __restrict__ c, float4* __restrict__ out) {
    int i = blockIdx.x * blockDim.x + threadIdx.x;  // over T*1024/4
    if (i >= T_TOK * (DMODEL / 4)) return;
    int t = i >> 8;  // 256 float4 per row
    int d = i & 255;
    float4 a = c[(size_t)(2 * t) * (DMODEL / 4) + d];
    float4 b = c[(size_t)(2 * t + 1) * (DMODEL / 4) + d];
    float4 o;
    o.x = a.x + b.x; o.y = a.y + b.y; o.z = a.z + b.z; o.w = a.w + b.w;
    out[i] = o;
}

// ---------------------------------------------------------------------------
extern "C" void kernel_launch(void* const* d_in, const int* in_sizes, int n_in,
                              void* d_out, int out_size, void* d_ws, size_t ws_size,
                              hipStream_t stream) {
    const float* x      = (const float*)d_in[0];
    const float* gate_w = (const float*)d_in[1];
    const float* w_up   = (const float*)d_in[2];
    const float* w_down = (const float*)d_in[3];
    const float* bias   = (const float*)d_in[4];
    float* out = (float*)d_out;

    // workspace layout (all chunks 16B-aligned)
    char* p = (char*)d_ws;
    int* counts = (int*)p;              p += 256;
    int* list   = (int*)p;              p += NEXP * T_TOK * 4;          // 64 KB
    float* w2   = (float*)p;            p += 4104 * 4;                  // 4097 used
    unsigned short* xb  = (unsigned short*)p;  p += (size_t)(T_TOK + 1) * DMODEL * 2;
    unsigned short* wub = (unsigned short*)p;  p += (size_t)NEXP * HID * DMODEL * 2;
    unsigned short* wdb = (unsigned short*)p;  p += (size_t)NEXP * HID * DMODEL * 2;
    unsigned short* h   = (unsigned short*)p;  p += (size_t)(2 * T_TOK + 1) * HID * 2;
    float* c            = (float*)p;           p += (size_t)(2 * T_TOK + 1) * DMODEL * 4;

    // 1. init counters / DUMP lists / zero dump token row
    init_k<<<64, 256, 0, stream>>>(counts, list, xb + (size_t)T_TOK * DMODEL);

    // 2. router (+ x -> bf16)
    router_k<<<T_TOK, 64, 0, stream>>>(x, gate_w, bias, xb, counts, list, w2);

    // 3. weights -> bf16
    convert_w<<<4096, 256, 0, stream>>>((const float4*)w_up, (const float4*)w_down,
                                        (ushort4*)wub, (ushort4*)wdb,
                                        NEXP * HID * DMODEL / 4);

    // 4. up-GEMM: h = bf16( w2 * relu(x @ Wu^T)^2 )
    moe_gemm<0><<<dim3(HID / 128, 16, NEXP), 256, 0, stream>>>(
        xb, list, counts, wub, w2, h, nullptr);

    // 5. down-GEMM: c[id] = h[id] @ Wd^T
    moe_gemm<1><<<dim3(DMODEL / 128, 16, NEXP), 256, 0, stream>>>(
        h, list, counts, wdb, w2, nullptr, c);

    // 6. combine the two assignments per token
    combine_k<<<(T_TOK * (DMODEL / 4) + 255) / 256, 256, 0, stream>>>(
        (const float4*)c, (float4*)out);
}